// Round 3
// baseline (1926.277 us; speedup 1.0000x reference)
//
#include <hip/hip_runtime.h>

#define KK 30
#define F 148
#define NNODE 16384

typedef short bf16x8 __attribute__((ext_vector_type(8)));
typedef float f32x4v __attribute__((ext_vector_type(4)));

// ---- bf16 helpers (RNE) ----
__device__ __forceinline__ ushort f2bf(float x) {
  unsigned u = __float_as_uint(x);
  unsigned r = (u + 0x7FFF + ((u >> 16) & 1)) >> 16;
  return (ushort)r;
}
__device__ __forceinline__ float bf2f(ushort b) { return __uint_as_float(((unsigned)b) << 16); }
__device__ __forceinline__ void bsplit(float x, ushort& h, ushort& l) {
  ushort hh = f2bf(x); h = hh; l = f2bf(x - bf2f(hh));
}

// ws layout (ushort offsets): pre-transposed split weights Bt[n][k]
#define B1HI 0
#define B1LO 17920   // 112*160
#define B2HI 35840
#define B2LO 50176   // 112*128
#define B3HI 64512
#define B3LO 78848

__global__ void prep_weights(const float* __restrict__ Ws1, const float* __restrict__ Ws2,
                             const float* __restrict__ Ws3, ushort* __restrict__ ws) {
  int i = blockIdx.x * 256 + threadIdx.x;
  if (i < 17920) {                       // B1: [112][160], src rows 100..231 of Ws1 [232][100]
    int n = i / 160, k = i % 160;
    float w = (n < 100 && k < 132) ? Ws1[(100 + k) * 100 + n] : 0.f;
    ushort h, l; bsplit(w, h, l);
    ws[B1HI + i] = h; ws[B1LO + i] = l;
  } else if (i < 17920 + 14336) {        // B2: [112][128], src Ws2 [116][100]
    int j = i - 17920; int n = j / 128, k = j % 128;
    float w = (n < 100 && k < 116) ? Ws2[k * 100 + n] : 0.f;
    ushort h, l; bsplit(w, h, l);
    ws[B2HI + j] = h; ws[B2LO + j] = l;
  } else if (i < 17920 + 2 * 14336) {    // B3: [112][128], src Ws3 [116][100]
    int j = i - 17920 - 14336; int n = j / 128, k = j % 128;
    float w = (n < 100 && k < 116) ? Ws3[k * 100 + n] : 0.f;
    ushort h, l; bsplit(w, h, l);
    ws[B3HI + j] = h; ws[B3LO + j] = l;
  }
}

#define DECL12 float a00=0,a01=0,a02=0,a10=0,a11=0,a12=0,a20=0,a21=0,a22=0,a30=0,a31=0,a32=0;
#define FMA3x4(v0_,v1_,v2_,w_) \
  a00=fmaf(v0_,w_.x,a00); a01=fmaf(v1_,w_.x,a01); a02=fmaf(v2_,w_.x,a02); \
  a10=fmaf(v0_,w_.y,a10); a11=fmaf(v1_,w_.y,a11); a12=fmaf(v2_,w_.y,a12); \
  a20=fmaf(v0_,w_.z,a20); a21=fmaf(v1_,w_.z,a21); a22=fmaf(v2_,w_.z,a22); \
  a30=fmaf(v0_,w_.w,a30); a31=fmaf(v1_,w_.w,a31); a32=fmaf(v2_,w_.w,a32);

#define GATE3(x0,x1,x2,d0,d1,d2) { float vn_=sqrtf((x0)*(x0)+(x1)*(x1)+(x2)*(x2)+1e-8f); \
  float g_=1.f/(1.f+expf(-vn_)); d0=(x0)*g_; d1=(x1)*g_; d2=(x2)*g_; }

// vector-path matvec, 4 outputs
template<int NI, bool GATEF>
__device__ __forceinline__ void vtask(const float* vsrc, const float* wbase, int wstride, float* vdst)
{
  DECL12
#pragma unroll 4
  for (int h = 0; h < NI; h++) {
    float v0 = vsrc[3*h], v1 = vsrc[3*h+1], v2 = vsrc[3*h+2];
    float4 w = *(const float4*)(wbase + h * wstride);
    FMA3x4(v0, v1, v2, w)
  }
  if (GATEF) {
    GATE3(a00,a01,a02, vdst[0],vdst[1],vdst[2])
    GATE3(a10,a11,a12, vdst[3],vdst[4],vdst[5])
    GATE3(a20,a21,a22, vdst[6],vdst[7],vdst[8])
    GATE3(a30,a31,a32, vdst[9],vdst[10],vdst[11])
  } else {
    vdst[0]=a00; vdst[1]=a01; vdst[2]=a02;  vdst[3]=a10; vdst[4]=a11; vdst[5]=a12;
    vdst[6]=a20; vdst[7]=a21; vdst[8]=a22;  vdst[9]=a30; vdst[10]=a31; vdst[11]=a32;
  }
}

// vh matvec: vectors fp32 + norms as split-bf16 into A cols
template<int NI>
__device__ __forceinline__ void vhtaskb(const float* vsrc, const float* wbase, int wstride,
                                        float* vdst, ushort* vnhi, ushort* vnlo)
{
  DECL12
#pragma unroll 4
  for (int h = 0; h < NI; h++) {
    float v0 = vsrc[3*h], v1 = vsrc[3*h+1], v2 = vsrc[3*h+2];
    float4 w = *(const float4*)(wbase + h * wstride);
    FMA3x4(v0, v1, v2, w)
  }
  vdst[0]=a00; vdst[1]=a01; vdst[2]=a02;  vdst[3]=a10; vdst[4]=a11; vdst[5]=a12;
  vdst[6]=a20; vdst[7]=a21; vdst[8]=a22;  vdst[9]=a30; vdst[10]=a31; vdst[11]=a32;
  float n0 = sqrtf(a00*a00+a01*a01+a02*a02 + 1e-8f); bsplit(n0, vnhi[0], vnlo[0]);
  float n1 = sqrtf(a10*a10+a11*a11+a12*a12 + 1e-8f); bsplit(n1, vnhi[1], vnlo[1]);
  float n2 = sqrtf(a20*a20+a21*a21+a22*a22 + 1e-8f); bsplit(n2, vnhi[2], vnlo[2]);
  float n3 = sqrtf(a30*a30+a31*a31+a32*a32 + 1e-8f); bsplit(n3, vnhi[3], vnlo[3]);
}

// split-bf16 MFMA over one n-tile, two m-tiles. A from LDS; B(hi/lo) pre-offset by n*BSTR.
template<int NKS>
__device__ __forceinline__ void mfma_nt(const ushort* A_hi, const ushort* A_lo, int astr,
                                        const ushort* B_hi, const ushort* B_lo,
                                        int lane, f32x4v& c0, f32x4v& c1)
{
  int r = lane & 15, q = lane >> 4;
  const int ka = q * 8;
#pragma unroll
  for (int ks = 0; ks < NKS; ks++) {
    int ko = ka + ks * 32;
    bf16x8 a0h = *(const bf16x8*)(A_hi + r * astr + ko);
    bf16x8 a0l = *(const bf16x8*)(A_lo + r * astr + ko);
    bf16x8 a1h = *(const bf16x8*)(A_hi + (16 + r) * astr + ko);
    bf16x8 a1l = *(const bf16x8*)(A_lo + (16 + r) * astr + ko);
    bf16x8 bh = *(const bf16x8*)(B_hi + ko);
    bf16x8 bl = *(const bf16x8*)(B_lo + ko);
    c0 = __builtin_amdgcn_mfma_f32_16x16x32_bf16(a0h, bh, c0, 0, 0, 0);
    c0 = __builtin_amdgcn_mfma_f32_16x16x32_bf16(a0h, bl, c0, 0, 0, 0);
    c0 = __builtin_amdgcn_mfma_f32_16x16x32_bf16(a0l, bh, c0, 0, 0, 0);
    c1 = __builtin_amdgcn_mfma_f32_16x16x32_bf16(a1h, bh, c1, 0, 0, 0);
    c1 = __builtin_amdgcn_mfma_f32_16x16x32_bf16(a1h, bl, c1, 0, 0, 0);
    c1 = __builtin_amdgcn_mfma_f32_16x16x32_bf16(a1l, bh, c1, 0, 0, 0);
  }
}

// LDS pool carving (floats)
#define P_SV   0      // 152
#define P_DH   152    // 148
#define P_VA   304    // 30*49
#define P_VB   1776   // 30*99
#define P_S1B  4748   // 100
#define P_MKA  4848   // 32
#define P_SBM  4880   // 30*100
#define P_A    7888   // A region, ushort-based
// A region (ushort offsets from P_A): A1hi [32][168]=5376, A1lo 5376, A2hi [32][136]=4352, A2lo 4352
#define A1S 168
#define A2S 136
#define POOL_F 17616  // 7888 + 9728

__global__ __launch_bounds__(256, 2)
void mpnn_fused(const float* __restrict__ h_V, const float* __restrict__ h_M,
                const int* __restrict__ mask_V, const int* __restrict__ mask_attend,
                const float* __restrict__ Wh1, const float* __restrict__ Wv1,
                const float* __restrict__ Ws1, const float* __restrict__ bs1,
                const float* __restrict__ Wh2, const float* __restrict__ Wv2,
                const float* __restrict__ bs2,
                const float* __restrict__ Wh3, const float* __restrict__ Wv3,
                const float* __restrict__ bs3,
                const float* __restrict__ Wh4, const float* __restrict__ Wv4,
                const float* __restrict__ Ws4, const float* __restrict__ bs4,
                const float* __restrict__ Wh5, const float* __restrict__ Wv5,
                const float* __restrict__ Ws5, const float* __restrict__ bs5,
                const float* __restrict__ ln0_g, const float* __restrict__ ln0_b,
                const float* __restrict__ ln1_g, const float* __restrict__ ln1_b,
                const ushort* __restrict__ wsb,
                float* __restrict__ out)
{
  __shared__ float pool[POOL_F];
  float* sv   = pool + P_SV;
  float* dh   = pool + P_DH;
  float* VAp  = pool + P_VA;   // stride 49
  float* VBp  = pool + P_VB;   // stride 99
  float* s1b  = pool + P_S1B;
  float* mka  = pool + P_MKA;
  float* sBm  = pool + P_SBM;  // stride 100 (s3 out fp32)
  ushort* A1hi = (ushort*)(pool + P_A);
  ushort* A1lo = A1hi + 5376;
  ushort* A2hi = A1lo + 5376;
  ushort* A2lo = A2hi + 4352;

  const int tid = threadIdx.x;
  const int node = blockIdx.x;
  const int wave = tid >> 6, lane = tid & 63;

  // ---- P0: stage node feats + edge feats + zero A pads ----
  for (int f = tid; f < 152; f += 256) sv[f] = (f < F) ? h_V[(long)node * F + f] : 0.f;
  if (tid < KK) mka[tid] = (float)mask_attend[node * KK + tid];
  for (int t = tid; t < 32 * 28; t += 256) { int r = t / 28, c = 132 + t % 28; A1hi[r*A1S+c] = 0; A1lo[r*A1S+c] = 0; }
  for (int t = tid; t < 32 * 12; t += 256) { int r = t / 12, c = 116 + t % 12; A2hi[r*A2S+c] = 0; A2lo[r*A2S+c] = 0; }
  for (int task = tid; task < KK * 37; task += 256) {
    int k = task / 37, q = task % 37;
    float4 d = *(const float4*)(h_M + ((long)node * KK + k) * F + q * 4);
    float vals[4] = {d.x, d.y, d.z, d.w};
#pragma unroll
    for (int u = 0; u < 4; u++) {
      int f = q * 4 + u;
      if (f < 48) VAp[k * 49 + f] = vals[u];
      else { int j = f - 48; bsplit(vals[u], A1hi[k*A1S + j], A1lo[k*A1S + j]); }
    }
  }
  __syncthreads();

  // ---- P1: vh1 (240 threads, 4h each) || s1base (16 threads) ----
  if (tid < 240) {
    int k = tid >> 3, h0 = (tid & 7) * 4;
    DECL12
#pragma unroll 4
    for (int i = 0; i < 16; i++) {            // vV rows (node feats)
      float v0 = sv[3*i], v1 = sv[3*i+1], v2 = sv[3*i+2];
      float4 w = *(const float4*)(Wh1 + i * 32 + h0);
      FMA3x4(v0, v1, v2, w)
    }
#pragma unroll 4
    for (int i = 0; i < 16; i++) {            // vM rows
      float v0 = VAp[k*49+3*i], v1 = VAp[k*49+3*i+1], v2 = VAp[k*49+3*i+2];
      float4 w = *(const float4*)(Wh1 + (16 + i) * 32 + h0);
      FMA3x4(v0, v1, v2, w)
    }
    float* vb = VBp + k * 99 + 3 * h0;
    vb[0]=a00; vb[1]=a01; vb[2]=a02;  vb[3]=a10; vb[4]=a11; vb[5]=a12;
    vb[6]=a20; vb[7]=a21; vb[8]=a22;  vb[9]=a30; vb[10]=a31; vb[11]=a32;
    ushort* nh = A1hi + k*A1S + 100 + h0; ushort* nl = A1lo + k*A1S + 100 + h0;
    float n0 = sqrtf(a00*a00+a01*a01+a02*a02 + 1e-8f); bsplit(n0, nh[0], nl[0]);
    float n1 = sqrtf(a10*a10+a11*a11+a12*a12 + 1e-8f); bsplit(n1, nh[1], nl[1]);
    float n2 = sqrtf(a20*a20+a21*a21+a22*a22 + 1e-8f); bsplit(n2, nh[2], nl[2]);
    float n3 = sqrtf(a30*a30+a31*a31+a32*a32 + 1e-8f); bsplit(n3, nh[3], nl[3]);
  } else {
    for (int qd = tid - 240; qd < 25; qd += 16) {
      int j0 = qd * 4;
      float4 acc = *(const float4*)(bs1 + j0);
      for (int i = 0; i < 100; i++) {
        float s = sv[48 + i];
        float4 w4 = *(const float4*)(Ws1 + i * 100 + j0);
        acc.x = fmaf(s, w4.x, acc.x); acc.y = fmaf(s, w4.y, acc.y);
        acc.z = fmaf(s, w4.z, acc.z); acc.w = fmaf(s, w4.w, acc.w);
      }
      *(float4*)(s1b + j0) = acc;
    }
  }
  __syncthreads();

  // ---- P2: s1 MFMA (waves 0-1) || v1 (waves 2-3) ----
  if (wave < 2) {
    int r = lane & 15, q = lane >> 4;
    int nt0 = (wave == 0) ? 0 : 4, nt1 = (wave == 0) ? 4 : 7;
    for (int nt = nt0; nt < nt1; nt++) {
      f32x4v c0 = {0,0,0,0}, c1 = {0,0,0,0};
      int n = nt * 16 + r;
      mfma_nt<5>(A1hi, A1lo, A1S, wsb + B1HI + n * 160, wsb + B1LO + n * 160, lane, c0, c1);
      if (n < 100) {
        float base = s1b[n];
#pragma unroll
        for (int reg = 0; reg < 4; reg++) {
          int m0 = q * 4 + reg;
          float x = fmaxf(c0[reg] + base, 0.f);
          bsplit(x, A2hi[m0*A2S + n], A2lo[m0*A2S + n]);
          int m1 = 16 + q * 4 + reg;
          if (m1 < 30) {
            float y = fmaxf(c1[reg] + base, 0.f);
            bsplit(y, A2hi[m1*A2S + n], A2lo[m1*A2S + n]);
          }
        }
      }
    }
  } else {
    int vt = tid - 128;
    if (vt < 120) { int k = vt >> 2, o0 = (vt & 3) * 4;
      vtask<32, true>(VBp + k*99, Wv1 + o0, 16, VAp + k*49 + 3*o0); }
  }
  __syncthreads();

  // ---- P3: vh2 (120 threads) ----
  if (tid < 120) {
    int k = tid >> 2, h0 = (tid & 3) * 4;
    vhtaskb<16>(VAp + k*49, Wh2 + h0, 16, VBp + k*99 + 3*h0,
                A2hi + k*A2S + 100 + h0, A2lo + k*A2S + 100 + h0);
  }
  __syncthreads();

  // ---- P4: s2 MFMA (waves 0-1) || v2 (waves 2-3) ----
  if (wave < 2) {
    int r = lane & 15, q = lane >> 4;
    int nt0 = (wave == 0) ? 0 : 4, nt1 = (wave == 0) ? 4 : 7;
    for (int nt = nt0; nt < nt1; nt++) {
      f32x4v c0 = {0,0,0,0}, c1 = {0,0,0,0};
      int n = nt * 16 + r;
      mfma_nt<4>(A2hi, A2lo, A2S, wsb + B2HI + n * 128, wsb + B2LO + n * 128, lane, c0, c1);
      if (n < 100) {
        float base = bs2[n];
#pragma unroll
        for (int reg = 0; reg < 4; reg++) {
          int m0 = q * 4 + reg;
          float x = fmaxf(c0[reg] + base, 0.f);
          bsplit(x, A1hi[m0*A1S + n], A1lo[m0*A1S + n]);
          int m1 = 16 + q * 4 + reg;
          if (m1 < 30) {
            float y = fmaxf(c1[reg] + base, 0.f);
            bsplit(y, A1hi[m1*A1S + n], A1lo[m1*A1S + n]);
          }
        }
      }
    }
  } else {
    int vt = tid - 128;
    if (vt < 120) { int k = vt >> 2, o0 = (vt & 3) * 4;
      vtask<16, true>(VBp + k*99, Wv2 + o0, 16, VAp + k*49 + 3*o0); }
  }
  __syncthreads();

  // ---- P5: vh3 (120 threads) || zero A1 cols 116..127 (16 threads) ----
  if (tid < 120) {
    int k = tid >> 2, h0 = (tid & 3) * 4;
    vhtaskb<16>(VAp + k*49, Wh3 + h0, 16, VBp + k*99 + 3*h0,
                A1hi + k*A1S + 100 + h0, A1lo + k*A1S + 100 + h0);
  } else if (tid >= 240) {
    for (int t = tid - 240; t < 32 * 12; t += 16) {
      int r = t / 12, c = 116 + t % 12;
      A1hi[r*A1S + c] = 0; A1lo[r*A1S + c] = 0;
    }
  }
  __syncthreads();

  // ---- P6: s3 MFMA (waves 0-1, fp32 out) || v3 (waves 2-3) ----
  if (wave < 2) {
    int r = lane & 15, q = lane >> 4;
    int nt0 = (wave == 0) ? 0 : 4, nt1 = (wave == 0) ? 4 : 7;
    for (int nt = nt0; nt < nt1; nt++) {
      f32x4v c0 = {0,0,0,0}, c1 = {0,0,0,0};
      int n = nt * 16 + r;
      mfma_nt<4>(A1hi, A1lo, A1S, wsb + B3HI + n * 128, wsb + B3LO + n * 128, lane, c0, c1);
      if (n < 100) {
        float base = bs3[n];
#pragma unroll
        for (int reg = 0; reg < 4; reg++) {
          int m0 = q * 4 + reg;
          sBm[m0 * 100 + n] = c0[reg] + base;
          int m1 = 16 + q * 4 + reg;
          if (m1 < 30) sBm[m1 * 100 + n] = c1[reg] + base;
        }
      }
    }
  } else {
    int vt = tid - 128;
    if (vt < 120) { int k = vt >> 2, o0 = (vt & 3) * 4;
      vtask<16, false>(VBp + k*99, Wv3 + o0, 16, VAp + k*49 + 3*o0); }
  }
  __syncthreads();

  // ---- P7: masked mean over K ----
  for (int f = tid; f < F; f += 256) {
    float acc = 0.f;
    if (f < 48) { for (int k = 0; k < KK; k++) acc += mka[k] * VAp[k*49 + f]; }
    else        { int j = f - 48; for (int k = 0; k < KK; k++) acc += mka[k] * sBm[k*100 + j]; }
    dh[f] = acc * (1.f / (float)KK);
  }
  __syncthreads();

  // ---- node phase (scratch aliases A region) ----
  float* ns   = pool + P_A;
  float* xb   = ns;          // 148
  float* hb   = ns + 160;    // 148
  float* nvh4 = ns + 320;    // 96
  float* nvn4 = ns + 416;    // 32
  float* s4   = ns + 448;    // 400 (+32 vn5 at 848 -> contiguous 432)
  float* nvn5 = ns + 848;    // 32
  float* v4   = ns + 880;    // 96
  float* nvh5 = ns + 976;    // 96
  float* v5   = ns + 1072;   // 48
  float* s5   = ns + 1120;   // 100
  float* red  = ns + 1220;   // 4
  float* part = ns + 1232;   // 800

  for (int f = tid; f < F; f += 256) xb[f] = sv[f] + dh[f];
  __syncthreads();
  // ln0 stats via wave shuffles
  if (tid < 64) {
    float a = (tid < 50) ? xb[48 + 2 * tid] : 0.f;
    float b = (tid < 50) ? xb[48 + 2 * tid + 1] : 0.f;
    float s = a + b, qq = a * a + b * b;
    for (int off = 32; off; off >>= 1) { s += __shfl_down(s, off); qq += __shfl_down(qq, off); }
    if (tid == 0) { red[1] = s * 0.01f; red[2] = qq * 0.01f; }
  } else if (tid < 128) {
    int l = tid - 64;
    float v = (l < 48) ? xb[l] : 0.f;
    float qq = v * v;
    for (int off = 32; off; off >>= 1) qq += __shfl_down(qq, off);
    if (l == 0) red[0] = sqrtf(qq * (1.f / 16.f) + 1e-8f);
  }
  __syncthreads();
  {
    float denom = red[0], mu = red[1];
    float var = red[2] - mu * mu;
    float rs = rsqrtf(var + 1e-5f);
    for (int f = tid; f < F; f += 256) {
      if (f < 48) hb[f] = xb[f] / denom;
      else { int j = f - 48; hb[f] = (xb[f] - mu) * rs * ln0_g[j] + ln0_b[j]; }
    }
  }
  __syncthreads();

  // GVP4: vh4 (16 -> 32)
  if (tid < 8) {
    int h0 = tid * 4;
    DECL12
#pragma unroll 4
    for (int i = 0; i < 16; i++) {
      float v0 = hb[3*i], v1 = hb[3*i+1], v2 = hb[3*i+2];
      float4 w = *(const float4*)(Wh4 + i * 32 + h0);
      FMA3x4(v0, v1, v2, w)
    }
    nvh4[3*(h0+0)+0]=a00; nvh4[3*(h0+0)+1]=a01; nvh4[3*(h0+0)+2]=a02;
    nvh4[3*(h0+1)+0]=a10; nvh4[3*(h0+1)+1]=a11; nvh4[3*(h0+1)+2]=a12;
    nvh4[3*(h0+2)+0]=a20; nvh4[3*(h0+2)+1]=a21; nvh4[3*(h0+2)+2]=a22;
    nvh4[3*(h0+3)+0]=a30; nvh4[3*(h0+3)+1]=a31; nvh4[3*(h0+3)+2]=a32;
    nvn4[h0+0] = sqrtf(a00*a00+a01*a01+a02*a02 + 1e-8f);
    nvn4[h0+1] = sqrtf(a10*a10+a11*a11+a12*a12 + 1e-8f);
    nvn4[h0+2] = sqrtf(a20*a20+a21*a21+a22*a22 + 1e-8f);
    nvn4[h0+3] = sqrtf(a30*a30+a31*a31+a32*a32 + 1e-8f);
  }
  __syncthreads();
  // s_out4 (400 outs, dot 132, relu; 200 threads x 2 cols) || v4 (gated)
  if (tid < 200) {
    int j0 = tid * 2;
    float ax = bs4[j0], ay = bs4[j0 + 1];
    const float* w = Ws4 + j0;
#pragma unroll 4
    for (int i = 0; i < 100; i++) {
      float s = hb[48 + i];
      float2 w2 = *(const float2*)(w + i * 400);
      ax = fmaf(s, w2.x, ax); ay = fmaf(s, w2.y, ay);
    }
#pragma unroll 4
    for (int h = 0; h < 32; h++) {
      float s = nvn4[h];
      float2 w2 = *(const float2*)(w + (100 + h) * 400);
      ax = fmaf(s, w2.x, ax); ay = fmaf(s, w2.y, ay);
    }
    s4[j0] = fmaxf(ax, 0.f); s4[j0 + 1] = fmaxf(ay, 0.f);
  } else if (tid >= 200 && tid < 208) {
    int o0 = (tid - 200) * 4;
    vtask<32, true>(nvh4, Wv4 + o0, 32, &v4[3 * o0]);
  }
  __syncthreads();
  // GVP5: vh5 (32 -> 32), vn5 contiguous after s4
  if (tid < 8) {
    int h0 = tid * 4;
    DECL12
#pragma unroll 4
    for (int i = 0; i < 32; i++) {
      float v0 = v4[3*i], v1 = v4[3*i+1], v2 = v4[3*i+2];
      float4 w = *(const float4*)(Wh5 + i * 32 + h0);
      FMA3x4(v0, v1, v2, w)
    }
    nvh5[3*(h0+0)+0]=a00; nvh5[3*(h0+0)+1]=a01; nvh5[3*(h0+0)+2]=a02;
    nvh5[3*(h0+1)+0]=a10; nvh5[3*(h0+1)+1]=a11; nvh5[3*(h0+1)+2]=a12;
    nvh5[3*(h0+2)+0]=a20; nvh5[3*(h0+2)+1]=a21; nvh5[3*(h0+2)+2]=a22;
    nvh5[3*(h0+3)+0]=a30; nvh5[3*(h0+3)+1]=a31; nvh5[3*(h0+3)+2]=a32;
    nvn5[h0+0] = sqrtf(a00*a00+a01*a01+a02*a02 + 1e-8f);
    nvn5[h0+1] = sqrtf(a10*a10+a11*a11+a12*a12 + 1e-8f);
    nvn5[h0+2] = sqrtf(a20*a20+a21*a21+a22*a22 + 1e-8f);
    nvn5[h0+3] = sqrtf(a30*a30+a31*a31+a32*a32 + 1e-8f);
  }
  __syncthreads();
  // s_out5 partials (dot 432 split 8 ways, 200 threads) || v5 (no gate)
  if (tid < 200) {
    int jq = tid / 8, c = tid % 8, j0 = jq * 4;
    int ibeg = c * 54, iend = ibeg + 54;
    float4 acc = make_float4(0.f, 0.f, 0.f, 0.f);
    const float* w = Ws5 + j0;
#pragma unroll 4
    for (int i = ibeg; i < iend; i++) {
      float s = s4[i];  // s4[0..399] then nvn5[0..31], contiguous
      float4 w4 = *(const float4*)(w + i * 100);
      acc.x = fmaf(s, w4.x, acc.x); acc.y = fmaf(s, w4.y, acc.y);
      acc.z = fmaf(s, w4.z, acc.z); acc.w = fmaf(s, w4.w, acc.w);
    }
    *(float4*)&part[tid * 4] = acc;
  } else if (tid >= 200 && tid < 204) {
    int o0 = (tid - 200) * 4;
    vtask<32, false>(nvh5, Wv5 + o0, 16, &v5[3 * o0]);
  }
  __syncthreads();
  if (tid < 25) {
    int j0 = tid * 4;
    float4 b = *(const float4*)(bs5 + j0);
    float4 acc = b;
#pragma unroll
    for (int c = 0; c < 8; c++) {
      float4 p = *(const float4*)&part[(tid * 8 + c) * 4];
      acc.x += p.x; acc.y += p.y; acc.z += p.z; acc.w += p.w;
    }
    *(float4*)&s5[j0] = acc;
  }
  __syncthreads();
  // x2 = h + dh2
  for (int f = tid; f < F; f += 256) {
    float d = (f < 48) ? v5[f] : s5[f - 48];
    xb[f] = hb[f] + d;
  }
  __syncthreads();
  // ln1 stats
  if (tid < 64) {
    float a = (tid < 50) ? xb[48 + 2 * tid] : 0.f;
    float b = (tid < 50) ? xb[48 + 2 * tid + 1] : 0.f;
    float s = a + b, qq = a * a + b * b;
    for (int off = 32; off; off >>= 1) { s += __shfl_down(s, off); qq += __shfl_down(qq, off); }
    if (tid == 0) { red[1] = s * 0.01f; red[2] = qq * 0.01f; }
  } else if (tid < 128) {
    int l = tid - 64;
    float v = (l < 48) ? xb[l] : 0.f;
    float qq = v * v;
    for (int off = 32; off; off >>= 1) qq += __shfl_down(qq, off);
    if (l == 0) red[0] = sqrtf(qq * (1.f / 16.f) + 1e-8f);
  }
  __syncthreads();
  {
    float denom = red[0], mu = red[1];
    float var = red[2] - mu * mu;
    float rs = rsqrtf(var + 1e-5f);
    float mv = (float)mask_V[node];
    for (int f = tid; f < F; f += 256) {
      float val;
      if (f < 48) val = xb[f] / denom;
      else { int j = f - 48; val = (xb[f] - mu) * rs * ln1_g[j] + ln1_b[j]; }
      out[(long)node * F + f] = mv * val;
    }
  }
}

extern "C" void kernel_launch(void* const* d_in, const int* in_sizes, int n_in,
                              void* d_out, int out_size, void* d_ws, size_t ws_size,
                              hipStream_t stream) {
  const float* h_V  = (const float*)d_in[0];
  const float* h_M  = (const float*)d_in[1];
  const int* mask_V = (const int*)d_in[2];
  const int* mask_attend = (const int*)d_in[3];
  const float* Wh1 = (const float*)d_in[4];
  const float* Wv1 = (const float*)d_in[5];
  const float* Ws1 = (const float*)d_in[6];
  const float* bs1 = (const float*)d_in[7];
  const float* Wh2 = (const float*)d_in[8];
  const float* Wv2 = (const float*)d_in[9];
  const float* Ws2 = (const float*)d_in[10];
  const float* bs2 = (const float*)d_in[11];
  const float* Wh3 = (const float*)d_in[12];
  const float* Wv3 = (const float*)d_in[13];
  const float* Ws3 = (const float*)d_in[14];
  const float* bs3 = (const float*)d_in[15];
  const float* Wh4 = (const float*)d_in[16];
  const float* Wv4 = (const float*)d_in[17];
  const float* Ws4 = (const float*)d_in[18];
  const float* bs4 = (const float*)d_in[19];
  const float* Wh5 = (const float*)d_in[20];
  const float* Wv5 = (const float*)d_in[21];
  const float* Ws5 = (const float*)d_in[22];
  const float* bs5 = (const float*)d_in[23];
  const float* ln0_g = (const float*)d_in[24];
  const float* ln0_b = (const float*)d_in[25];
  const float* ln1_g = (const float*)d_in[26];
  const float* ln1_b = (const float*)d_in[27];
  float* out = (float*)d_out;
  ushort* wsb = (ushort*)d_ws;

  prep_weights<<<dim3(182), dim3(256), 0, stream>>>(Ws1, Ws2, Ws3, wsb);
  mpnn_fused<<<dim3(NNODE), dim3(256), 0, stream>>>(
      h_V, h_M, mask_V, mask_attend,
      Wh1, Wv1, Ws1, bs1, Wh2, Wv2, bs2, Wh3, Wv3, bs3,
      Wh4, Wv4, Ws4, bs4, Wh5, Wv5, Ws5, bs5,
      ln0_g, ln0_b, ln1_g, ln1_b, wsb, out);
}

// Round 4
// 1625.658 us; speedup vs baseline: 1.1849x; 1.1849x over previous
//
#include <hip/hip_runtime.h>

#define KK 30
#define F 148
#define NNODE 16384

typedef short bf16x8 __attribute__((ext_vector_type(8)));
typedef float f32x4v __attribute__((ext_vector_type(4)));

// ---- bf16 helpers (RNE) ----
__device__ __forceinline__ ushort f2bf(float x) {
  unsigned u = __float_as_uint(x);
  unsigned r = (u + 0x7FFF + ((u >> 16) & 1)) >> 16;
  return (ushort)r;
}
__device__ __forceinline__ float bf2f(ushort b) { return __uint_as_float(((unsigned)b) << 16); }
__device__ __forceinline__ void bsplit(float x, ushort& h, ushort& l) {
  ushort hh = f2bf(x); h = hh; l = f2bf(x - bf2f(hh));
}

// ws layout (ushort offsets): pre-transposed split weights Bt[n][k], hi+lo
#define B1HI 0
#define B1LO 17920   // 112*160
#define B2HI 35840
#define B2LO 50176   // 112*128
#define B3HI 64512
#define B3LO 78848

__global__ void prep_weights(const float* __restrict__ Ws1, const float* __restrict__ Ws2,
                             const float* __restrict__ Ws3, ushort* __restrict__ ws) {
  int i = blockIdx.x * 256 + threadIdx.x;
  if (i < 17920) {                       // B1: [112][160], src rows 100..231 of Ws1 [232][100]
    int n = i / 160, k = i % 160;
    float w = (n < 100 && k < 132) ? Ws1[(100 + k) * 100 + n] : 0.f;
    ushort h, l; bsplit(w, h, l);
    ws[B1HI + i] = h; ws[B1LO + i] = l;
  } else if (i < 17920 + 14336) {        // B2: [112][128], src Ws2 [116][100]
    int j = i - 17920; int n = j / 128, k = j % 128;
    float w = (n < 100 && k < 116) ? Ws2[k * 100 + n] : 0.f;
    ushort h, l; bsplit(w, h, l);
    ws[B2HI + j] = h; ws[B2LO + j] = l;
  } else if (i < 17920 + 2 * 14336) {    // B3: [112][128], src Ws3 [116][100]
    int j = i - 17920 - 14336; int n = j / 128, k = j % 128;
    float w = (n < 100 && k < 116) ? Ws3[k * 100 + n] : 0.f;
    ushort h, l; bsplit(w, h, l);
    ws[B3HI + j] = h; ws[B3LO + j] = l;
  }
}

#define DECL12 float a00=0,a01=0,a02=0,a10=0,a11=0,a12=0,a20=0,a21=0,a22=0,a30=0,a31=0,a32=0;
#define FMA3x4(v0_,v1_,v2_,w_) \
  a00=fmaf(v0_,w_.x,a00); a01=fmaf(v1_,w_.x,a01); a02=fmaf(v2_,w_.x,a02); \
  a10=fmaf(v0_,w_.y,a10); a11=fmaf(v1_,w_.y,a11); a12=fmaf(v2_,w_.y,a12); \
  a20=fmaf(v0_,w_.z,a20); a21=fmaf(v1_,w_.z,a21); a22=fmaf(v2_,w_.z,a22); \
  a30=fmaf(v0_,w_.w,a30); a31=fmaf(v1_,w_.w,a31); a32=fmaf(v2_,w_.w,a32);

#define GATE3(x0,x1,x2,d0,d1,d2) { float vn_=sqrtf((x0)*(x0)+(x1)*(x1)+(x2)*(x2)+1e-8f); \
  float g_=1.f/(1.f+expf(-vn_)); d0=(x0)*g_; d1=(x1)*g_; d2=(x2)*g_; }

// vector-path matvec, 4 outputs
template<int NI, bool GATEF>
__device__ __forceinline__ void vtask(const float* vsrc, const float* wbase, int wstride, float* vdst)
{
  DECL12
#pragma unroll 4
  for (int h = 0; h < NI; h++) {
    float v0 = vsrc[3*h], v1 = vsrc[3*h+1], v2 = vsrc[3*h+2];
    float4 w = *(const float4*)(wbase + h * wstride);
    FMA3x4(v0, v1, v2, w)
  }
  if (GATEF) {
    GATE3(a00,a01,a02, vdst[0],vdst[1],vdst[2])
    GATE3(a10,a11,a12, vdst[3],vdst[4],vdst[5])
    GATE3(a20,a21,a22, vdst[6],vdst[7],vdst[8])
    GATE3(a30,a31,a32, vdst[9],vdst[10],vdst[11])
  } else {
    vdst[0]=a00; vdst[1]=a01; vdst[2]=a02;  vdst[3]=a10; vdst[4]=a11; vdst[5]=a12;
    vdst[6]=a20; vdst[7]=a21; vdst[8]=a22;  vdst[9]=a30; vdst[10]=a31; vdst[11]=a32;
  }
}

// vh matvec: vectors fp32 + norms packed bf16 (2 dwords) into A cols (dword-aligned)
template<int NI>
__device__ __forceinline__ void vhtaskb(const float* vsrc, const float* wbase, int wstride,
                                        float* vdst, ushort* ncol)
{
  DECL12
#pragma unroll 4
  for (int h = 0; h < NI; h++) {
    float v0 = vsrc[3*h], v1 = vsrc[3*h+1], v2 = vsrc[3*h+2];
    float4 w = *(const float4*)(wbase + h * wstride);
    FMA3x4(v0, v1, v2, w)
  }
  vdst[0]=a00; vdst[1]=a01; vdst[2]=a02;  vdst[3]=a10; vdst[4]=a11; vdst[5]=a12;
  vdst[6]=a20; vdst[7]=a21; vdst[8]=a22;  vdst[9]=a30; vdst[10]=a31; vdst[11]=a32;
  float n0 = sqrtf(a00*a00+a01*a01+a02*a02 + 1e-8f);
  float n1 = sqrtf(a10*a10+a11*a11+a12*a12 + 1e-8f);
  float n2 = sqrtf(a20*a20+a21*a21+a22*a22 + 1e-8f);
  float n3 = sqrtf(a30*a30+a31*a31+a32*a32 + 1e-8f);
  unsigned* p = (unsigned*)ncol;
  p[0] = (unsigned)f2bf(n0) | ((unsigned)f2bf(n1) << 16);
  p[1] = (unsigned)f2bf(n2) | ((unsigned)f2bf(n3) << 16);
}

// 2-term split-bf16 MFMA over one n-tile, two m-tiles. A hi-only from LDS; B hi+lo from L2.
template<int NKS>
__device__ __forceinline__ void mfma_nt2(const ushort* __restrict__ A, int astr,
                                         const ushort* __restrict__ B_hi,
                                         const ushort* __restrict__ B_lo,
                                         int lane, f32x4v& c0, f32x4v& c1)
{
  int r = lane & 15, q = lane >> 4;
  const int ka = q * 8;
#pragma unroll
  for (int ks = 0; ks < NKS; ks++) {
    int ko = ka + ks * 32;
    bf16x8 a0 = *(const bf16x8*)(A + r * astr + ko);
    bf16x8 a1 = *(const bf16x8*)(A + (16 + r) * astr + ko);
    bf16x8 bh = *(const bf16x8*)(B_hi + ko);
    bf16x8 bl = *(const bf16x8*)(B_lo + ko);
    c0 = __builtin_amdgcn_mfma_f32_16x16x32_bf16(a0, bh, c0, 0, 0, 0);
    c0 = __builtin_amdgcn_mfma_f32_16x16x32_bf16(a0, bl, c0, 0, 0, 0);
    c1 = __builtin_amdgcn_mfma_f32_16x16x32_bf16(a1, bh, c1, 0, 0, 0);
    c1 = __builtin_amdgcn_mfma_f32_16x16x32_bf16(a1, bl, c1, 0, 0, 0);
  }
}

// LDS pool carving (floats)
#define P_SV   0      // 152
#define P_DH   152    // 148
#define P_VA   304    // 30*49
#define P_VB   1776   // 30*99
#define P_S1B  4748   // 100
#define P_MKA  4848   // 32
#define P_SBM  4880   // 30*100
#define P_A    7888   // A region (ushort-based): A1 [32][168]=5376u, A2 [32][136]=4352u
#define A1S 168
#define A2S 136
#define POOL_F 12752  // 7888 + (5376+4352)/2

__global__ __launch_bounds__(256, 3)
void mpnn_fused(const float* __restrict__ h_V, const float* __restrict__ h_M,
                const int* __restrict__ mask_V, const int* __restrict__ mask_attend,
                const float* __restrict__ Wh1, const float* __restrict__ Wv1,
                const float* __restrict__ Ws1, const float* __restrict__ bs1,
                const float* __restrict__ Wh2, const float* __restrict__ Wv2,
                const float* __restrict__ bs2,
                const float* __restrict__ Wh3, const float* __restrict__ Wv3,
                const float* __restrict__ bs3,
                const float* __restrict__ Wh4, const float* __restrict__ Wv4,
                const float* __restrict__ Ws4, const float* __restrict__ bs4,
                const float* __restrict__ Wh5, const float* __restrict__ Wv5,
                const float* __restrict__ Ws5, const float* __restrict__ bs5,
                const float* __restrict__ ln0_g, const float* __restrict__ ln0_b,
                const float* __restrict__ ln1_g, const float* __restrict__ ln1_b,
                const ushort* __restrict__ wsb,
                float* __restrict__ out)
{
  __shared__ float pool[POOL_F];
  float* sv   = pool + P_SV;
  float* dh   = pool + P_DH;
  float* VAp  = pool + P_VA;   // stride 49
  float* VBp  = pool + P_VB;   // stride 99
  float* s1b  = pool + P_S1B;
  float* mka  = pool + P_MKA;
  float* sBm  = pool + P_SBM;  // stride 100 (s3 out fp32)
  ushort* A1 = (ushort*)(pool + P_A);   // [32][A1S]
  ushort* A2 = A1 + 5376;               // [32][A2S]

  const int tid = threadIdx.x;
  const int node = blockIdx.x;
  const int wave = tid >> 6, lane = tid & 63;

  // ---- P0: stage node feats + edge feats + zero A pads ----
  for (int f = tid; f < 152; f += 256) sv[f] = (f < F) ? h_V[(long)node * F + f] : 0.f;
  if (tid < KK) mka[tid] = (float)mask_attend[node * KK + tid];
  // zero A1 cols 132..159 (14 dwords x 32 rows), A2 cols 116..127 (6 dwords x 32 rows)
  for (int t = tid; t < 448; t += 256) {
    int r = t / 14, c2 = t % 14;
    ((unsigned*)A1)[((r * A1S + 132) >> 1) + c2] = 0;
  }
  for (int t = tid; t < 192; t += 256) {
    int r = t / 6, c2 = t % 6;
    ((unsigned*)A2)[((r * A2S + 116) >> 1) + c2] = 0;
  }
  for (int task = tid; task < KK * 37; task += 256) {
    int k = task / 37, q = task % 37;
    float4 d = *(const float4*)(h_M + ((long)node * KK + k) * F + q * 4);
    if (q < 12) {
      float vals[4] = {d.x, d.y, d.z, d.w};
#pragma unroll
      for (int u = 0; u < 4; u++) VAp[k * 49 + q * 4 + u] = vals[u];
    } else {
      int j0 = q * 4 - 48;
      unsigned* p = (unsigned*)(A1 + k * A1S + j0);
      p[0] = (unsigned)f2bf(d.x) | ((unsigned)f2bf(d.y) << 16);
      p[1] = (unsigned)f2bf(d.z) | ((unsigned)f2bf(d.w) << 16);
    }
  }
  __syncthreads();

  // ---- P1: vh1 (240 threads, 4h each) || s1base (16 threads) ----
  if (tid < 240) {
    int k = tid >> 3, h0 = (tid & 7) * 4;
    DECL12
#pragma unroll 4
    for (int i = 0; i < 16; i++) {            // vV rows (node feats)
      float v0 = sv[3*i], v1 = sv[3*i+1], v2 = sv[3*i+2];
      float4 w = *(const float4*)(Wh1 + i * 32 + h0);
      FMA3x4(v0, v1, v2, w)
    }
#pragma unroll 4
    for (int i = 0; i < 16; i++) {            // vM rows
      float v0 = VAp[k*49+3*i], v1 = VAp[k*49+3*i+1], v2 = VAp[k*49+3*i+2];
      float4 w = *(const float4*)(Wh1 + (16 + i) * 32 + h0);
      FMA3x4(v0, v1, v2, w)
    }
    float* vb = VBp + k * 99 + 3 * h0;
    vb[0]=a00; vb[1]=a01; vb[2]=a02;  vb[3]=a10; vb[4]=a11; vb[5]=a12;
    vb[6]=a20; vb[7]=a21; vb[8]=a22;  vb[9]=a30; vb[10]=a31; vb[11]=a32;
    float n0 = sqrtf(a00*a00+a01*a01+a02*a02 + 1e-8f);
    float n1 = sqrtf(a10*a10+a11*a11+a12*a12 + 1e-8f);
    float n2 = sqrtf(a20*a20+a21*a21+a22*a22 + 1e-8f);
    float n3 = sqrtf(a30*a30+a31*a31+a32*a32 + 1e-8f);
    unsigned* p = (unsigned*)(A1 + k * A1S + 100 + h0);
    p[0] = (unsigned)f2bf(n0) | ((unsigned)f2bf(n1) << 16);
    p[1] = (unsigned)f2bf(n2) | ((unsigned)f2bf(n3) << 16);
  } else {
    for (int qd = tid - 240; qd < 25; qd += 16) {
      int j0 = qd * 4;
      float4 acc = *(const float4*)(bs1 + j0);
      for (int i = 0; i < 100; i++) {
        float s = sv[48 + i];
        float4 w4 = *(const float4*)(Ws1 + i * 100 + j0);
        acc.x = fmaf(s, w4.x, acc.x); acc.y = fmaf(s, w4.y, acc.y);
        acc.z = fmaf(s, w4.z, acc.z); acc.w = fmaf(s, w4.w, acc.w);
      }
      *(float4*)(s1b + j0) = acc;
    }
  }
  __syncthreads();

  // ---- P2: s1 MFMA (waves 0-1) || v1 (waves 2-3) ----
  if (wave < 2) {
    int r = lane & 15, q = lane >> 4;
    int nt0 = (wave == 0) ? 0 : 4, nt1 = (wave == 0) ? 4 : 7;
    for (int nt = nt0; nt < nt1; nt++) {
      f32x4v c0 = {0,0,0,0}, c1 = {0,0,0,0};
      int n = nt * 16 + r;
      mfma_nt2<5>(A1, A1S, wsb + B1HI + n * 160, wsb + B1LO + n * 160, lane, c0, c1);
      float base = (n < 100) ? s1b[n] : 0.f;
      unsigned* dst = (unsigned*)A2;
#pragma unroll
      for (int reg = 0; reg < 4; reg++) {
        int m0 = q * 4 + reg, m1 = m0 + 16;
        unsigned hx = f2bf(fmaxf(c0[reg] + base, 0.f));
        unsigned ox = __shfl_down(hx, 1);
        unsigned hy = f2bf(fmaxf(c1[reg] + base, 0.f));
        unsigned oy = __shfl_down(hy, 1);
        if (((lane & 1) == 0) && n < 100) {
          dst[(m0 * A2S + n) >> 1] = hx | (ox << 16);
          if (m1 < 30) dst[(m1 * A2S + n) >> 1] = hy | (oy << 16);
        }
      }
    }
  } else {
    int vt = tid - 128;
    if (vt < 120) { int k = vt >> 2, o0 = (vt & 3) * 4;
      vtask<32, true>(VBp + k*99, Wv1 + o0, 16, VAp + k*49 + 3*o0); }
  }
  __syncthreads();

  // ---- P3: vh2 (120 threads) ----
  if (tid < 120) {
    int k = tid >> 2, h0 = (tid & 3) * 4;
    vhtaskb<16>(VAp + k*49, Wh2 + h0, 16, VBp + k*99 + 3*h0, A2 + k*A2S + 100 + h0);
  }
  __syncthreads();

  // ---- P4: s2 MFMA (waves 0-1) || v2 (waves 2-3) ----
  if (wave < 2) {
    int r = lane & 15, q = lane >> 4;
    int nt0 = (wave == 0) ? 0 : 4, nt1 = (wave == 0) ? 4 : 7;
    for (int nt = nt0; nt < nt1; nt++) {
      f32x4v c0 = {0,0,0,0}, c1 = {0,0,0,0};
      int n = nt * 16 + r;
      mfma_nt2<4>(A2, A2S, wsb + B2HI + n * 128, wsb + B2LO + n * 128, lane, c0, c1);
      float base = (n < 100) ? bs2[n] : 0.f;
      unsigned* dst = (unsigned*)A1;
#pragma unroll
      for (int reg = 0; reg < 4; reg++) {
        int m0 = q * 4 + reg, m1 = m0 + 16;
        unsigned hx = f2bf(fmaxf(c0[reg] + base, 0.f));
        unsigned ox = __shfl_down(hx, 1);
        unsigned hy = f2bf(fmaxf(c1[reg] + base, 0.f));
        unsigned oy = __shfl_down(hy, 1);
        if (((lane & 1) == 0) && n < 100) {
          dst[(m0 * A1S + n) >> 1] = hx | (ox << 16);
          if (m1 < 30) dst[(m1 * A1S + n) >> 1] = hy | (oy << 16);
        }
      }
    }
  } else {
    int vt = tid - 128;
    if (vt < 120) { int k = vt >> 2, o0 = (vt & 3) * 4;
      vtask<16, true>(VBp + k*99, Wv2 + o0, 16, VAp + k*49 + 3*o0); }
  }
  __syncthreads();

  // ---- P5: vh3 (120 threads) || zero A1 cols 116..127 (16 threads) ----
  if (tid < 120) {
    int k = tid >> 2, h0 = (tid & 3) * 4;
    vhtaskb<16>(VAp + k*49, Wh3 + h0, 16, VBp + k*99 + 3*h0, A1 + k*A1S + 100 + h0);
  } else if (tid >= 240) {
    for (int t = tid - 240; t < 192; t += 16) {
      int r = t / 6, c2 = t % 6;
      ((unsigned*)A1)[((r * A1S + 116) >> 1) + c2] = 0;
    }
  }
  __syncthreads();

  // ---- P6: s3 MFMA (waves 0-1, fp32 out) || v3 (waves 2-3) ----
  if (wave < 2) {
    int r = lane & 15, q = lane >> 4;
    int nt0 = (wave == 0) ? 0 : 4, nt1 = (wave == 0) ? 4 : 7;
    for (int nt = nt0; nt < nt1; nt++) {
      f32x4v c0 = {0,0,0,0}, c1 = {0,0,0,0};
      int n = nt * 16 + r;
      mfma_nt2<4>(A1, A1S, wsb + B3HI + n * 128, wsb + B3LO + n * 128, lane, c0, c1);
      if (n < 100) {
        float base = bs3[n];
#pragma unroll
        for (int reg = 0; reg < 4; reg++) {
          int m0 = q * 4 + reg, m1 = m0 + 16;
          sBm[m0 * 100 + n] = c0[reg] + base;
          if (m1 < 30) sBm[m1 * 100 + n] = c1[reg] + base;
        }
      }
    }
  } else {
    int vt = tid - 128;
    if (vt < 120) { int k = vt >> 2, o0 = (vt & 3) * 4;
      vtask<16, false>(VBp + k*99, Wv3 + o0, 16, VAp + k*49 + 3*o0); }
  }
  __syncthreads();

  // ---- P7: masked mean over K ----
  for (int f = tid; f < F; f += 256) {
    float acc = 0.f;
    if (f < 48) { for (int k = 0; k < KK; k++) acc += mka[k] * VAp[k*49 + f]; }
    else        { int j = f - 48; for (int k = 0; k < KK; k++) acc += mka[k] * sBm[k*100 + j]; }
    dh[f] = acc * (1.f / (float)KK);
  }
  __syncthreads();

  // ---- node phase (scratch aliases A region) ----
  float* ns   = pool + P_A;
  float* xb   = ns;          // 148
  float* hb   = ns + 160;    // 148
  float* nvh4 = ns + 320;    // 96
  float* nvn4 = ns + 416;    // 32
  float* s4   = ns + 448;    // 400 (+32 vn5 at 848 -> contiguous 432)
  float* nvn5 = ns + 848;    // 32
  float* v4   = ns + 880;    // 96
  float* nvh5 = ns + 976;    // 96
  float* v5   = ns + 1072;   // 48
  float* s5   = ns + 1120;   // 100
  float* red  = ns + 1220;   // 4
  float* part = ns + 1232;   // 800

  for (int f = tid; f < F; f += 256) xb[f] = sv[f] + dh[f];
  __syncthreads();
  // ln0 stats via wave shuffles
  if (tid < 64) {
    float a = (tid < 50) ? xb[48 + 2 * tid] : 0.f;
    float b = (tid < 50) ? xb[48 + 2 * tid + 1] : 0.f;
    float s = a + b, qq = a * a + b * b;
    for (int off = 32; off; off >>= 1) { s += __shfl_down(s, off); qq += __shfl_down(qq, off); }
    if (tid == 0) { red[1] = s * 0.01f; red[2] = qq * 0.01f; }
  } else if (tid < 128) {
    int l = tid - 64;
    float v = (l < 48) ? xb[l] : 0.f;
    float qq = v * v;
    for (int off = 32; off; off >>= 1) qq += __shfl_down(qq, off);
    if (l == 0) red[0] = sqrtf(qq * (1.f / 16.f) + 1e-8f);
  }
  __syncthreads();
  {
    float denom = red[0], mu = red[1];
    float var = red[2] - mu * mu;
    float rs = rsqrtf(var + 1e-5f);
    for (int f = tid; f < F; f += 256) {
      if (f < 48) hb[f] = xb[f] / denom;
      else { int j = f - 48; hb[f] = (xb[f] - mu) * rs * ln0_g[j] + ln0_b[j]; }
    }
  }
  __syncthreads();

  // GVP4: vh4 (16 -> 32)
  if (tid < 8) {
    int h0 = tid * 4;
    DECL12
#pragma unroll 4
    for (int i = 0; i < 16; i++) {
      float v0 = hb[3*i], v1 = hb[3*i+1], v2 = hb[3*i+2];
      float4 w = *(const float4*)(Wh4 + i * 32 + h0);
      FMA3x4(v0, v1, v2, w)
    }
    nvh4[3*(h0+0)+0]=a00; nvh4[3*(h0+0)+1]=a01; nvh4[3*(h0+0)+2]=a02;
    nvh4[3*(h0+1)+0]=a10; nvh4[3*(h0+1)+1]=a11; nvh4[3*(h0+1)+2]=a12;
    nvh4[3*(h0+2)+0]=a20; nvh4[3*(h0+2)+1]=a21; nvh4[3*(h0+2)+2]=a22;
    nvh4[3*(h0+3)+0]=a30; nvh4[3*(h0+3)+1]=a31; nvh4[3*(h0+3)+2]=a32;
    nvn4[h0+0] = sqrtf(a00*a00+a01*a01+a02*a02 + 1e-8f);
    nvn4[h0+1] = sqrtf(a10*a10+a11*a11+a12*a12 + 1e-8f);
    nvn4[h0+2] = sqrtf(a20*a20+a21*a21+a22*a22 + 1e-8f);
    nvn4[h0+3] = sqrtf(a30*a30+a31*a31+a32*a32 + 1e-8f);
  }
  __syncthreads();
  // s_out4 (400 outs, dot 132, relu; 200 threads x 2 cols) || v4 (gated)
  if (tid < 200) {
    int j0 = tid * 2;
    float ax = bs4[j0], ay = bs4[j0 + 1];
    const float* w = Ws4 + j0;
#pragma unroll 4
    for (int i = 0; i < 100; i++) {
      float s = hb[48 + i];
      float2 w2 = *(const float2*)(w + i * 400);
      ax = fmaf(s, w2.x, ax); ay = fmaf(s, w2.y, ay);
    }
#pragma unroll 4
    for (int h = 0; h < 32; h++) {
      float s = nvn4[h];
      float2 w2 = *(const float2*)(w + (100 + h) * 400);
      ax = fmaf(s, w2.x, ax); ay = fmaf(s, w2.y, ay);
    }
    s4[j0] = fmaxf(ax, 0.f); s4[j0 + 1] = fmaxf(ay, 0.f);
  } else if (tid >= 200 && tid < 208) {
    int o0 = (tid - 200) * 4;
    vtask<32, true>(nvh4, Wv4 + o0, 32, &v4[3 * o0]);
  }
  __syncthreads();
  // GVP5: vh5 (32 -> 32), vn5 contiguous after s4
  if (tid < 8) {
    int h0 = tid * 4;
    DECL12
#pragma unroll 4
    for (int i = 0; i < 32; i++) {
      float v0 = v4[3*i], v1 = v4[3*i+1], v2 = v4[3*i+2];
      float4 w = *(const float4*)(Wh5 + i * 32 + h0);
      FMA3x4(v0, v1, v2, w)
    }
    nvh5[3*(h0+0)+0]=a00; nvh5[3*(h0+0)+1]=a01; nvh5[3*(h0+0)+2]=a02;
    nvh5[3*(h0+1)+0]=a10; nvh5[3*(h0+1)+1]=a11; nvh5[3*(h0+1)+2]=a12;
    nvh5[3*(h0+2)+0]=a20; nvh5[3*(h0+2)+1]=a21; nvh5[3*(h0+2)+2]=a22;
    nvh5[3*(h0+3)+0]=a30; nvh5[3*(h0+3)+1]=a31; nvh5[3*(h0+3)+2]=a32;
    nvn5[h0+0] = sqrtf(a00*a00+a01*a01+a02*a02 + 1e-8f);
    nvn5[h0+1] = sqrtf(a10*a10+a11*a11+a12*a12 + 1e-8f);
    nvn5[h0+2] = sqrtf(a20*a20+a21*a21+a22*a22 + 1e-8f);
    nvn5[h0+3] = sqrtf(a30*a30+a31*a31+a32*a32 + 1e-8f);
  }
  __syncthreads();
  // s_out5 partials (dot 432 split 8 ways, 200 threads) || v5 (no gate)
  if (tid < 200) {
    int jq = tid / 8, c = tid % 8, j0 = jq * 4;
    int ibeg = c * 54, iend = ibeg + 54;
    float4 acc = make_float4(0.f, 0.f, 0.f, 0.f);
    const float* w = Ws5 + j0;
#pragma unroll 4
    for (int i = ibeg; i < iend; i++) {
      float s = s4[i];  // s4[0..399] then nvn5[0..31], contiguous
      float4 w4 = *(const float4*)(w + i * 100);
      acc.x = fmaf(s, w4.x, acc.x); acc.y = fmaf(s, w4.y, acc.y);
      acc.z = fmaf(s, w4.z, acc.z); acc.w = fmaf(s, w4.w, acc.w);
    }
    *(float4*)&part[tid * 4] = acc;
  } else if (tid >= 200 && tid < 204) {
    int o0 = (tid - 200) * 4;
    vtask<32, false>(nvh5, Wv5 + o0, 16, &v5[3 * o0]);
  }
  __syncthreads();
  if (tid < 25) {
    int j0 = tid * 4;
    float4 b = *(const float4*)(bs5 + j0);
    float4 acc = b;
#pragma unroll
    for (int c = 0; c < 8; c++) {
      float4 p = *(const float4*)&part[(tid * 8 + c) * 4];
      acc.x += p.x; acc.y += p.y; acc.z += p.z; acc.w += p.w;
    }
    *(float4*)&s5[j0] = acc;
  }
  __syncthreads();
  // x2 = h + dh2
  for (int f = tid; f < F; f += 256) {
    float d = (f < 48) ? v5[f] : s5[f - 48];
    xb[f] = hb[f] + d;
  }
  __syncthreads();
  // ln1 stats
  if (tid < 64) {
    float a = (tid < 50) ? xb[48 + 2 * tid] : 0.f;
    float b = (tid < 50) ? xb[48 + 2 * tid + 1] : 0.f;
    float s = a + b, qq = a * a + b * b;
    for (int off = 32; off; off >>= 1) { s += __shfl_down(s, off); qq += __shfl_down(qq, off); }
    if (tid == 0) { red[1] = s * 0.01f; red[2] = qq * 0.01f; }
  } else if (tid < 128) {
    int l = tid - 64;
    float v = (l < 48) ? xb[l] : 0.f;
    float qq = v * v;
    for (int off = 32; off; off >>= 1) qq += __shfl_down(qq, off);
    if (l == 0) red[0] = sqrtf(qq * (1.f / 16.f) + 1e-8f);
  }
  __syncthreads();
  {
    float denom = red[0], mu = red[1];
    float var = red[2] - mu * mu;
    float rs = rsqrtf(var + 1e-5f);
    float mv = (float)mask_V[node];
    for (int f = tid; f < F; f += 256) {
      float val;
      if (f < 48) val = xb[f] / denom;
      else { int j = f - 48; val = (xb[f] - mu) * rs * ln1_g[j] + ln1_b[j]; }
      out[(long)node * F + f] = mv * val;
    }
  }
}

extern "C" void kernel_launch(void* const* d_in, const int* in_sizes, int n_in,
                              void* d_out, int out_size, void* d_ws, size_t ws_size,
                              hipStream_t stream) {
  const float* h_V  = (const float*)d_in[0];
  const float* h_M  = (const float*)d_in[1];
  const int* mask_V = (const int*)d_in[2];
  const int* mask_attend = (const int*)d_in[3];
  const float* Wh1 = (const float*)d_in[4];
  const float* Wv1 = (const float*)d_in[5];
  const float* Ws1 = (const float*)d_in[6];
  const float* bs1 = (const float*)d_in[7];
  const float* Wh2 = (const float*)d_in[8];
  const float* Wv2 = (const float*)d_in[9];
  const float* Ws2 = (const float*)d_in[10];
  const float* bs2 = (const float*)d_in[11];
  const float* Wh3 = (const float*)d_in[12];
  const float* Wv3 = (const float*)d_in[13];
  const float* Ws3 = (const float*)d_in[14];
  const float* bs3 = (const float*)d_in[15];
  const float* Wh4 = (const float*)d_in[16];
  const float* Wv4 = (const float*)d_in[17];
  const float* Ws4 = (const float*)d_in[18];
  const float* bs4 = (const float*)d_in[19];
  const float* Wh5 = (const float*)d_in[20];
  const float* Wv5 = (const float*)d_in[21];
  const float* Ws5 = (const float*)d_in[22];
  const float* bs5 = (const float*)d_in[23];
  const float* ln0_g = (const float*)d_in[24];
  const float* ln0_b = (const float*)d_in[25];
  const float* ln1_g = (const float*)d_in[26];
  const float* ln1_b = (const float*)d_in[27];
  float* out = (float*)d_out;
  ushort* wsb = (ushort*)d_ws;

  prep_weights<<<dim3(182), dim3(256), 0, stream>>>(Ws1, Ws2, Ws3, wsb);
  mpnn_fused<<<dim3(NNODE), dim3(256), 0, stream>>>(
      h_V, h_M, mask_V, mask_attend,
      Wh1, Wv1, Ws1, bs1, Wh2, Wv2, bs2, Wh3, Wv3, bs3,
      Wh4, Wv4, Ws4, bs4, Wh5, Wv5, Ws5, bs5,
      ln0_g, ln0_b, ln1_g, ln1_b, wsb, out);
}

// Round 6
// 1389.082 us; speedup vs baseline: 1.3867x; 1.1703x over previous
//
#include <hip/hip_runtime.h>

#define KK 30
#define F 148
#define NNODE 16384

typedef short bf16x8 __attribute__((ext_vector_type(8)));
typedef float f32x4v __attribute__((ext_vector_type(4)));

// ---- bf16 helpers (RNE) ----
__device__ __forceinline__ ushort f2bf(float x) {
  unsigned u = __float_as_uint(x);
  unsigned r = (u + 0x7FFF + ((u >> 16) & 1)) >> 16;
  return (ushort)r;
}
__device__ __forceinline__ float bf2f(ushort b) { return __uint_as_float(((unsigned)b) << 16); }
__device__ __forceinline__ void bsplit(float x, ushort& h, ushort& l) {
  ushort hh = f2bf(x); h = hh; l = f2bf(x - bf2f(hh));
}

// d_ws layout: [ s1bg 16384*100 fl ][ vhbg 16384*96 fl ][ wsb ushorts ]
#define WS_S1B 0
#define WS_VHB (NNODE * 100)
#define WS_WSB (NNODE * 100 + NNODE * 96)
// wsb (ushort offsets): pre-transposed split weights Bt[n][k], hi+lo
#define B1HI 0
#define B1LO 17920   // 112*160
#define B2HI 35840
#define B2LO 50176   // 112*128
#define B3HI 64512
#define B3LO 78848

__global__ void prep_weights(const float* __restrict__ Ws1, const float* __restrict__ Ws2,
                             const float* __restrict__ Ws3, ushort* __restrict__ ws) {
  int i = blockIdx.x * 256 + threadIdx.x;
  if (i < 17920) {                       // B1: [112][160], src rows 100..231 of Ws1 [232][100]
    int n = i / 160, k = i % 160;
    float w = (n < 100 && k < 132) ? Ws1[(100 + k) * 100 + n] : 0.f;
    ushort h, l; bsplit(w, h, l);
    ws[B1HI + i] = h; ws[B1LO + i] = l;
  } else if (i < 17920 + 14336) {        // B2: [112][128], src Ws2 [116][100]
    int j = i - 17920; int n = j / 128, k = j % 128;
    float w = (n < 100 && k < 116) ? Ws2[k * 100 + n] : 0.f;
    ushort h, l; bsplit(w, h, l);
    ws[B2HI + j] = h; ws[B2LO + j] = l;
  } else if (i < 17920 + 2 * 14336) {    // B3: [112][128], src Ws3 [116][100]
    int j = i - 17920 - 14336; int n = j / 128, k = j % 128;
    float w = (n < 100 && k < 116) ? Ws3[k * 100 + n] : 0.f;
    ushort h, l; bsplit(w, h, l);
    ws[B3HI + j] = h; ws[B3LO + j] = l;
  }
}

// per-node k-independent precompute: s1base (bias + sV@Ws1[0:100]) and vhb (vV@Wh1[0:16])
// NEEDS 132 active threads (100 + 32) -> block = 192 (R5 bug: block was 128, h=28..31 never written)
__global__ __launch_bounds__(192)
void prep_node(const float* __restrict__ h_V, const float* __restrict__ Ws1,
               const float* __restrict__ bs1, const float* __restrict__ Wh1,
               float* __restrict__ s1bg, float* __restrict__ vhbg) {
  __shared__ float sv[148];
  const int node = blockIdx.x, tid = threadIdx.x;
  for (int f = tid; f < F; f += 192) sv[f] = h_V[(long)node * F + f];
  __syncthreads();
  if (tid < 100) {
    float acc = bs1[tid];
#pragma unroll 4
    for (int i = 0; i < 100; i++) acc = fmaf(sv[48 + i], Ws1[i * 100 + tid], acc);
    s1bg[node * 100 + tid] = acc;
  } else if (tid < 132) {
    int h = tid - 100;
    float a0 = 0.f, a1 = 0.f, a2 = 0.f;
#pragma unroll 4
    for (int i = 0; i < 16; i++) {
      float w = Wh1[i * 32 + h];
      a0 = fmaf(sv[3*i], w, a0); a1 = fmaf(sv[3*i+1], w, a1); a2 = fmaf(sv[3*i+2], w, a2);
    }
    vhbg[node * 96 + 3*h + 0] = a0;
    vhbg[node * 96 + 3*h + 1] = a1;
    vhbg[node * 96 + 3*h + 2] = a2;
  }
}

#define DECL12 float a00=0,a01=0,a02=0,a10=0,a11=0,a12=0,a20=0,a21=0,a22=0,a30=0,a31=0,a32=0;
#define FMA3x4(v0_,v1_,v2_,w_) \
  a00=fmaf(v0_,w_.x,a00); a01=fmaf(v1_,w_.x,a01); a02=fmaf(v2_,w_.x,a02); \
  a10=fmaf(v0_,w_.y,a10); a11=fmaf(v1_,w_.y,a11); a12=fmaf(v2_,w_.y,a12); \
  a20=fmaf(v0_,w_.z,a20); a21=fmaf(v1_,w_.z,a21); a22=fmaf(v2_,w_.z,a22); \
  a30=fmaf(v0_,w_.w,a30); a31=fmaf(v1_,w_.w,a31); a32=fmaf(v2_,w_.w,a32);

#define GATE3(x0,x1,x2,d0,d1,d2) { float vn_=sqrtf((x0)*(x0)+(x1)*(x1)+(x2)*(x2)+1e-8f); \
  float g_=1.f/(1.f+expf(-vn_)); d0=(x0)*g_; d1=(x1)*g_; d2=(x2)*g_; }

// vector-path matvec, 4 outputs
template<int NI, bool GATEF>
__device__ __forceinline__ void vtask(const float* vsrc, const float* wbase, int wstride, float* vdst)
{
  DECL12
#pragma unroll 4
  for (int h = 0; h < NI; h++) {
    float v0 = vsrc[3*h], v1 = vsrc[3*h+1], v2 = vsrc[3*h+2];
    float4 w = *(const float4*)(wbase + h * wstride);
    FMA3x4(v0, v1, v2, w)
  }
  if (GATEF) {
    GATE3(a00,a01,a02, vdst[0],vdst[1],vdst[2])
    GATE3(a10,a11,a12, vdst[3],vdst[4],vdst[5])
    GATE3(a20,a21,a22, vdst[6],vdst[7],vdst[8])
    GATE3(a30,a31,a32, vdst[9],vdst[10],vdst[11])
  } else {
    vdst[0]=a00; vdst[1]=a01; vdst[2]=a02;  vdst[3]=a10; vdst[4]=a11; vdst[5]=a12;
    vdst[6]=a20; vdst[7]=a21; vdst[8]=a22;  vdst[9]=a30; vdst[10]=a31; vdst[11]=a32;
  }
}

// vh matvec: vectors fp32 + norms packed bf16 (2 dwords) into A cols (dword-aligned)
template<int NI>
__device__ __forceinline__ void vhtaskb(const float* vsrc, const float* wbase, int wstride,
                                        float* vdst, ushort* ncol)
{
  DECL12
#pragma unroll 4
  for (int h = 0; h < NI; h++) {
    float v0 = vsrc[3*h], v1 = vsrc[3*h+1], v2 = vsrc[3*h+2];
    float4 w = *(const float4*)(wbase + h * wstride);
    FMA3x4(v0, v1, v2, w)
  }
  vdst[0]=a00; vdst[1]=a01; vdst[2]=a02;  vdst[3]=a10; vdst[4]=a11; vdst[5]=a12;
  vdst[6]=a20; vdst[7]=a21; vdst[8]=a22;  vdst[9]=a30; vdst[10]=a31; vdst[11]=a32;
  float n0 = sqrtf(a00*a00+a01*a01+a02*a02 + 1e-8f);
  float n1 = sqrtf(a10*a10+a11*a11+a12*a12 + 1e-8f);
  float n2 = sqrtf(a20*a20+a21*a21+a22*a22 + 1e-8f);
  float n3 = sqrtf(a30*a30+a31*a31+a32*a32 + 1e-8f);
  unsigned* p = (unsigned*)ncol;
  p[0] = (unsigned)f2bf(n0) | ((unsigned)f2bf(n1) << 16);
  p[1] = (unsigned)f2bf(n2) | ((unsigned)f2bf(n3) << 16);
}

// 2-term split-bf16 MFMA over one n-tile, two m-tiles. A hi-only from LDS; B hi+lo from L2.
template<int NKS>
__device__ __forceinline__ void mfma_nt2(const ushort* __restrict__ A, int astr,
                                         const ushort* __restrict__ B_hi,
                                         const ushort* __restrict__ B_lo,
                                         int lane, f32x4v& c0, f32x4v& c1)
{
  int r = lane & 15, q = lane >> 4;
  const int ka = q * 8;
#pragma unroll
  for (int ks = 0; ks < NKS; ks++) {
    int ko = ka + ks * 32;
    bf16x8 a0 = *(const bf16x8*)(A + r * astr + ko);
    bf16x8 a1 = *(const bf16x8*)(A + (16 + r) * astr + ko);
    bf16x8 bh = *(const bf16x8*)(B_hi + ko);
    bf16x8 bl = *(const bf16x8*)(B_lo + ko);
    c0 = __builtin_amdgcn_mfma_f32_16x16x32_bf16(a0, bh, c0, 0, 0, 0);
    c0 = __builtin_amdgcn_mfma_f32_16x16x32_bf16(a0, bl, c0, 0, 0, 0);
    c1 = __builtin_amdgcn_mfma_f32_16x16x32_bf16(a1, bh, c1, 0, 0, 0);
    c1 = __builtin_amdgcn_mfma_f32_16x16x32_bf16(a1, bl, c1, 0, 0, 0);
  }
}

// LDS pool carving (float offsets)
#define P_SV   0      // 148
#define P_VA   148    // VAp [30][49] fp32
#define P_VB   1618   // VBp [30][97] fp32
#define P_MKB  4528   // 1 (ballot mask)
#define P_A    4532   // A1 ushort [32][168] = 2688 fl (byte 18128, 16B-aligned)
#define P_A2   7220   // A2 ushort [32][136] = 2176 fl; sBm fp32 [30][100] = 3000 fl (aliased, A2 dead after P4)
#define A1S 168
#define A2S 136
#define POOL_F 10220  // 40880 B -> 4 blocks/CU

__global__ __launch_bounds__(256, 4)
void mpnn_fused(const float* __restrict__ h_V, const float* __restrict__ h_M,
                const int* __restrict__ mask_V, const int* __restrict__ mask_attend,
                const float* __restrict__ Wh1, const float* __restrict__ Wv1,
                const float* __restrict__ Wv2, const float* __restrict__ bs2,
                const float* __restrict__ Wv3, const float* __restrict__ bs3,
                const float* __restrict__ Wh2, const float* __restrict__ Wh3,
                const float* __restrict__ Wh4, const float* __restrict__ Wv4,
                const float* __restrict__ Ws4, const float* __restrict__ bs4,
                const float* __restrict__ Wh5, const float* __restrict__ Wv5,
                const float* __restrict__ Ws5, const float* __restrict__ bs5,
                const float* __restrict__ ln0_g, const float* __restrict__ ln0_b,
                const float* __restrict__ ln1_g, const float* __restrict__ ln1_b,
                const float* __restrict__ s1bg, const float* __restrict__ vhbg,
                const ushort* __restrict__ wsb,
                float* __restrict__ out)
{
  __shared__ float pool[POOL_F];
  float* sv   = pool + P_SV;
  float* VAp  = pool + P_VA;   // stride 49
  float* VBp  = pool + P_VB;   // stride 97
  float* sBm  = pool + P_A2;   // stride 100 (s3 out fp32, aliases A2)
  ushort* A1 = (ushort*)(pool + P_A);   // [32][A1S]
  ushort* A2 = (ushort*)(pool + P_A2);  // [32][A2S]

  const int tid = threadIdx.x;
  const int node = blockIdx.x;
  const int wave = tid >> 6, lane = tid & 63;

  // ---- P0: stage node feats + edge feats + zero A pads + mask ballot ----
  for (int f = tid; f < F; f += 256) sv[f] = h_V[(long)node * F + f];
  {
    unsigned long long bal = __ballot(tid < KK && mask_attend[node * KK + tid] != 0);
    if (tid == 0) *(unsigned*)(pool + P_MKB) = (unsigned)bal;
  }
  // zero A1 cols 132..159 (14 dwords x 32 rows), A2 cols 116..127 (6 dwords x 32 rows)
  for (int t = tid; t < 448; t += 256) {
    int r = t / 14, c2 = t % 14;
    ((unsigned*)A1)[((r * A1S + 132) >> 1) + c2] = 0;
  }
  for (int t = tid; t < 192; t += 256) {
    int r = t / 6, c2 = t % 6;
    ((unsigned*)A2)[((r * A2S + 116) >> 1) + c2] = 0;
  }
  for (int task = tid; task < KK * 37; task += 256) {
    int k = task / 37, q = task % 37;
    float4 d = *(const float4*)(h_M + ((long)node * KK + k) * F + q * 4);
    if (q < 12) {
      VAp[k * 49 + q * 4 + 0] = d.x; VAp[k * 49 + q * 4 + 1] = d.y;
      VAp[k * 49 + q * 4 + 2] = d.z; VAp[k * 49 + q * 4 + 3] = d.w;
    } else {
      int j0 = q * 4 - 48;
      unsigned* p = (unsigned*)(A1 + k * A1S + j0);
      p[0] = (unsigned)f2bf(d.x) | ((unsigned)f2bf(d.y) << 16);
      p[1] = (unsigned)f2bf(d.z) | ((unsigned)f2bf(d.w) << 16);
    }
  }
  __syncthreads();

  // ---- P1: vh1 (240 threads, 4h each; node-half from vhbg) ----
  if (tid < 240) {
    int k = tid >> 3, h0 = (tid & 7) * 4;
    const float4* vb4 = (const float4*)(vhbg + (long)node * 96 + 3 * h0);
    float4 q0 = vb4[0], q1 = vb4[1], q2 = vb4[2];
    float a00=q0.x,a01=q0.y,a02=q0.z, a10=q0.w,a11=q1.x,a12=q1.y,
          a20=q1.z,a21=q1.w,a22=q2.x, a30=q2.y,a31=q2.z,a32=q2.w;
#pragma unroll 4
    for (int i = 0; i < 16; i++) {            // vM rows
      float v0 = VAp[k*49+3*i], v1 = VAp[k*49+3*i+1], v2 = VAp[k*49+3*i+2];
      float4 w = *(const float4*)(Wh1 + (16 + i) * 32 + h0);
      FMA3x4(v0, v1, v2, w)
    }
    float* vb = VBp + k * 97 + 3 * h0;
    vb[0]=a00; vb[1]=a01; vb[2]=a02;  vb[3]=a10; vb[4]=a11; vb[5]=a12;
    vb[6]=a20; vb[7]=a21; vb[8]=a22;  vb[9]=a30; vb[10]=a31; vb[11]=a32;
    float n0 = sqrtf(a00*a00+a01*a01+a02*a02 + 1e-8f);
    float n1 = sqrtf(a10*a10+a11*a11+a12*a12 + 1e-8f);
    float n2 = sqrtf(a20*a20+a21*a21+a22*a22 + 1e-8f);
    float n3 = sqrtf(a30*a30+a31*a31+a32*a32 + 1e-8f);
    unsigned* p = (unsigned*)(A1 + k * A1S + 100 + h0);
    p[0] = (unsigned)f2bf(n0) | ((unsigned)f2bf(n1) << 16);
    p[1] = (unsigned)f2bf(n2) | ((unsigned)f2bf(n3) << 16);
  }
  __syncthreads();

  // ---- P2: s1 MFMA (waves 0-1) || v1 (waves 2-3) ----
  if (wave < 2) {
    int r = lane & 15, q = lane >> 4;
    int nt0 = (wave == 0) ? 0 : 4, nt1 = (wave == 0) ? 4 : 7;
    for (int nt = nt0; nt < nt1; nt++) {
      int n = nt * 16 + r;
      float base = (n < 100) ? s1bg[(long)node * 100 + n] : 0.f;
      f32x4v c0 = {0,0,0,0}, c1 = {0,0,0,0};
      mfma_nt2<5>(A1, A1S, wsb + B1HI + n * 160, wsb + B1LO + n * 160, lane, c0, c1);
      unsigned* dst = (unsigned*)A2;
#pragma unroll
      for (int reg = 0; reg < 4; reg++) {
        int m0 = q * 4 + reg, m1 = m0 + 16;
        unsigned hx = f2bf(fmaxf(c0[reg] + base, 0.f));
        unsigned ox = __shfl_down(hx, 1);
        unsigned hy = f2bf(fmaxf(c1[reg] + base, 0.f));
        unsigned oy = __shfl_down(hy, 1);
        if (((lane & 1) == 0) && n < 100) {
          dst[(m0 * A2S + n) >> 1] = hx | (ox << 16);
          if (m1 < 30) dst[(m1 * A2S + n) >> 1] = hy | (oy << 16);
        }
      }
    }
  } else {
    int vt = tid - 128;
    if (vt < 120) { int k = vt >> 2, o0 = (vt & 3) * 4;
      vtask<32, true>(VBp + k*97, Wv1 + o0, 16, VAp + k*49 + 3*o0); }
  }
  __syncthreads();

  // ---- P3: vh2 (120 threads) ----
  if (tid < 120) {
    int k = tid >> 2, h0 = (tid & 3) * 4;
    vhtaskb<16>(VAp + k*49, Wh2 + h0, 16, VBp + k*97 + 3*h0, A2 + k*A2S + 100 + h0);
  }
  __syncthreads();

  // ---- P4: s2 MFMA (waves 0-1) || v2 (waves 2-3) ----
  if (wave < 2) {
    int r = lane & 15, q = lane >> 4;
    int nt0 = (wave == 0) ? 0 : 4, nt1 = (wave == 0) ? 4 : 7;
    for (int nt = nt0; nt < nt1; nt++) {
      f32x4v c0 = {0,0,0,0}, c1 = {0,0,0,0};
      int n = nt * 16 + r;
      mfma_nt2<4>(A2, A2S, wsb + B2HI + n * 128, wsb + B2LO + n * 128, lane, c0, c1);
      float base = (n < 100) ? bs2[n] : 0.f;
      unsigned* dst = (unsigned*)A1;
#pragma unroll
      for (int reg = 0; reg < 4; reg++) {
        int m0 = q * 4 + reg, m1 = m0 + 16;
        unsigned hx = f2bf(fmaxf(c0[reg] + base, 0.f));
        unsigned ox = __shfl_down(hx, 1);
        unsigned hy = f2bf(fmaxf(c1[reg] + base, 0.f));
        unsigned oy = __shfl_down(hy, 1);
        if (((lane & 1) == 0) && n < 100) {
          dst[(m0 * A1S + n) >> 1] = hx | (ox << 16);
          if (m1 < 30) dst[(m1 * A1S + n) >> 1] = hy | (oy << 16);
        }
      }
    }
  } else {
    int vt = tid - 128;
    if (vt < 120) { int k = vt >> 2, o0 = (vt & 3) * 4;
      vtask<16, true>(VBp + k*97, Wv2 + o0, 16, VAp + k*49 + 3*o0); }
  }
  __syncthreads();

  // ---- P5: vh3 (120 threads) || zero A1 cols 116..127 (16 threads) ----
  if (tid < 120) {
    int k = tid >> 2, h0 = (tid & 3) * 4;
    vhtaskb<16>(VAp + k*49, Wh3 + h0, 16, VBp + k*97 + 3*h0, A1 + k*A1S + 100 + h0);
  } else if (tid >= 240) {
    for (int t = tid - 240; t < 192; t += 16) {
      int r = t / 6, c2 = t % 6;
      ((unsigned*)A1)[((r * A1S + 116) >> 1) + c2] = 0;
    }
  }
  __syncthreads();

  // ---- P6: s3 MFMA (waves 0-1, fp32 out -> sBm aliasing dead A2) || v3 (waves 2-3) ----
  if (wave < 2) {
    int r = lane & 15, q = lane >> 4;
    int nt0 = (wave == 0) ? 0 : 4, nt1 = (wave == 0) ? 4 : 7;
    for (int nt = nt0; nt < nt1; nt++) {
      f32x4v c0 = {0,0,0,0}, c1 = {0,0,0,0};
      int n = nt * 16 + r;
      mfma_nt2<4>(A1, A1S, wsb + B3HI + n * 128, wsb + B3LO + n * 128, lane, c0, c1);
      if (n < 100) {
        float base = bs3[n];
#pragma unroll
        for (int reg = 0; reg < 4; reg++) {
          int m0 = q * 4 + reg, m1 = m0 + 16;
          sBm[m0 * 100 + n] = c0[reg] + base;
          if (m1 < 30) sBm[m1 * 100 + n] = c1[reg] + base;
        }
      }
    }
  } else {
    int vt = tid - 128;
    if (vt < 120) { int k = vt >> 2, o0 = (vt & 3) * 4;
      vtask<16, false>(VBp + k*97, Wv3 + o0, 16, VAp + k*49 + 3*o0); }
  }
  __syncthreads();

  // ---- node phase scratch aliases A1 region (dead after P6) ----
  float* ns   = pool + P_A;
  float* xb   = ns;          // 148
  float* hb   = ns + 160;    // 148
  float* nvh4 = ns + 320;    // 96
  float* nvn4 = ns + 416;    // 32
  float* s4   = ns + 448;    // 400 (+32 vn5 at 848 -> contiguous 432)
  float* nvn5 = ns + 848;    // 32
  float* v4   = ns + 880;    // 96
  float* nvh5 = ns + 976;    // 96
  float* v5   = ns + 1072;   // 48
  float* s5   = ns + 1120;   // 100
  float* red  = ns + 1220;   // 4
  float* part = ns + 1232;   // 800  (ends 2032 < 2688)

  // ---- P7: masked mean over K -> xb = sv + dh ----
  {
    unsigned mkb = *(unsigned*)(pool + P_MKB);
    for (int f = tid; f < F; f += 256) {
      float acc = 0.f;
      if (f < 48) { for (int k = 0; k < KK; k++) if ((mkb >> k) & 1) acc += VAp[k*49 + f]; }
      else        { int j = f - 48; for (int k = 0; k < KK; k++) if ((mkb >> k) & 1) acc += sBm[k*100 + j]; }
      xb[f] = sv[f] + acc * (1.f / (float)KK);
    }
  }
  __syncthreads();
  // ln0 stats via wave shuffles
  if (tid < 64) {
    float a = (tid < 50) ? xb[48 + 2 * tid] : 0.f;
    float b = (tid < 50) ? xb[48 + 2 * tid + 1] : 0.f;
    float s = a + b, qq = a * a + b * b;
    for (int off = 32; off; off >>= 1) { s += __shfl_down(s, off); qq += __shfl_down(qq, off); }
    if (tid == 0) { red[1] = s * 0.01f; red[2] = qq * 0.01f; }
  } else if (tid < 128) {
    int l = tid - 64;
    float v = (l < 48) ? xb[l] : 0.f;
    float qq = v * v;
    for (int off = 32; off; off >>= 1) qq += __shfl_down(qq, off);
    if (l == 0) red[0] = sqrtf(qq * (1.f / 16.f) + 1e-8f);
  }
  __syncthreads();
  {
    float denom = red[0], mu = red[1];
    float var = red[2] - mu * mu;
    float rs = rsqrtf(var + 1e-5f);
    for (int f = tid; f < F; f += 256) {
      if (f < 48) hb[f] = xb[f] / denom;
      else { int j = f - 48; hb[f] = (xb[f] - mu) * rs * ln0_g[j] + ln0_b[j]; }
    }
  }
  __syncthreads();

  // GVP4: vh4 (16 -> 32), 32 threads, 1 h each
  if (tid < 32) {
    int h = tid;
    float a0 = 0.f, a1 = 0.f, a2 = 0.f;
#pragma unroll 4
    for (int i = 0; i < 16; i++) {
      float w = Wh4[i * 32 + h];
      a0 = fmaf(hb[3*i], w, a0); a1 = fmaf(hb[3*i+1], w, a1); a2 = fmaf(hb[3*i+2], w, a2);
    }
    nvh4[3*h] = a0; nvh4[3*h+1] = a1; nvh4[3*h+2] = a2;
    nvn4[h] = sqrtf(a0*a0 + a1*a1 + a2*a2 + 1e-8f);
  }
  __syncthreads();
  // s_out4 (400 outs, dot 132, relu; 200 threads x 2 cols) || v4 (32 threads, wave 3)
  if (tid < 200) {
    int j0 = tid * 2;
    float ax = bs4[j0], ay = bs4[j0 + 1];
    const float* w = Ws4 + j0;
#pragma unroll 4
    for (int i = 0; i < 100; i++) {
      float s = hb[48 + i];
      float2 w2 = *(const float2*)(w + i * 400);
      ax = fmaf(s, w2.x, ax); ay = fmaf(s, w2.y, ay);
    }
#pragma unroll 4
    for (int h = 0; h < 32; h++) {
      float s = nvn4[h];
      float2 w2 = *(const float2*)(w + (100 + h) * 400);
      ax = fmaf(s, w2.x, ax); ay = fmaf(s, w2.y, ay);
    }
    s4[j0] = fmaxf(ax, 0.f); s4[j0 + 1] = fmaxf(ay, 0.f);
  } else if (tid >= 224) {
    int o = tid - 224;
    float a0 = 0.f, a1 = 0.f, a2 = 0.f;
#pragma unroll 4
    for (int h = 0; h < 32; h++) {
      float w = Wv4[h * 32 + o];
      a0 = fmaf(nvh4[3*h], w, a0); a1 = fmaf(nvh4[3*h+1], w, a1); a2 = fmaf(nvh4[3*h+2], w, a2);
    }
    GATE3(a0, a1, a2, v4[3*o], v4[3*o+1], v4[3*o+2])
  }
  __syncthreads();
  // GVP5: vh5 (32 -> 32), 32 threads
  if (tid < 32) {
    int h = tid;
    float a0 = 0.f, a1 = 0.f, a2 = 0.f;
#pragma unroll 4
    for (int i = 0; i < 32; i++) {
      float w = Wh5[i * 32 + h];
      a0 = fmaf(v4[3*i], w, a0); a1 = fmaf(v4[3*i+1], w, a1); a2 = fmaf(v4[3*i+2], w, a2);
    }
    nvh5[3*h] = a0; nvh5[3*h+1] = a1; nvh5[3*h+2] = a2;
    nvn5[h] = sqrtf(a0*a0 + a1*a1 + a2*a2 + 1e-8f);
  }
  __syncthreads();
  // s_out5 partials (dot 432 split 8 ways, 200 threads) || v5 (16 threads, wave 3)
  if (tid < 200) {
    int jq = tid / 8, c = tid % 8, j0 = jq * 4;
    int ibeg = c * 54, iend = ibeg + 54;
    float4 acc = make_float4(0.f, 0.f, 0.f, 0.f);
    const float* w = Ws5 + j0;
#pragma unroll 4
    for (int i = ibeg; i < iend; i++) {
      float s = s4[i];  // s4[0..399] then nvn5[0..31], contiguous
      float4 w4 = *(const float4*)(w + i * 100);
      acc.x = fmaf(s, w4.x, acc.x); acc.y = fmaf(s, w4.y, acc.y);
      acc.z = fmaf(s, w4.z, acc.z); acc.w = fmaf(s, w4.w, acc.w);
    }
    *(float4*)&part[tid * 4] = acc;
  } else if (tid >= 224 && tid < 240) {
    int o = tid - 224;
    float a0 = 0.f, a1 = 0.f, a2 = 0.f;
#pragma unroll 4
    for (int h = 0; h < 32; h++) {
      float w = Wv5[h * 16 + o];
      a0 = fmaf(nvh5[3*h], w, a0); a1 = fmaf(nvh5[3*h+1], w, a1); a2 = fmaf(nvh5[3*h+2], w, a2);
    }
    v5[3*o] = a0; v5[3*o+1] = a1; v5[3*o+2] = a2;
  }
  __syncthreads();
  if (tid < 25) {
    int j0 = tid * 4;
    float4 b = *(const float4*)(bs5 + j0);
    float4 acc = b;
#pragma unroll
    for (int c = 0; c < 8; c++) {
      float4 p = *(const float4*)&part[(tid * 8 + c) * 4];
      acc.x += p.x; acc.y += p.y; acc.z += p.z; acc.w += p.w;
    }
    *(float4*)&s5[j0] = acc;
  }
  __syncthreads();
  // x2 = h + dh2
  for (int f = tid; f < F; f += 256) {
    float d = (f < 48) ? v5[f] : s5[f - 48];
    xb[f] = hb[f] + d;
  }
  __syncthreads();
  // ln1 stats
  if (tid < 64) {
    float a = (tid < 50) ? xb[48 + 2 * tid] : 0.f;
    float b = (tid < 50) ? xb[48 + 2 * tid + 1] : 0.f;
    float s = a + b, qq = a * a + b * b;
    for (int off = 32; off; off >>= 1) { s += __shfl_down(s, off); qq += __shfl_down(qq, off); }
    if (tid == 0) { red[1] = s * 0.01f; red[2] = qq * 0.01f; }
  } else if (tid < 128) {
    int l = tid - 64;
    float v = (l < 48) ? xb[l] : 0.f;
    float qq = v * v;
    for (int off = 32; off; off >>= 1) qq += __shfl_down(qq, off);
    if (l == 0) red[0] = sqrtf(qq * (1.f / 16.f) + 1e-8f);
  }
  __syncthreads();
  {
    float denom = red[0], mu = red[1];
    float var = red[2] - mu * mu;
    float rs = rsqrtf(var + 1e-5f);
    float mv = (float)mask_V[node];
    for (int f = tid; f < F; f += 256) {
      float val;
      if (f < 48) val = xb[f] / denom;
      else { int j = f - 48; val = (xb[f] - mu) * rs * ln1_g[j] + ln1_b[j]; }
      out[(long)node * F + f] = mv * val;
    }
  }
}

extern "C" void kernel_launch(void* const* d_in, const int* in_sizes, int n_in,
                              void* d_out, int out_size, void* d_ws, size_t ws_size,
                              hipStream_t stream) {
  const float* h_V  = (const float*)d_in[0];
  const float* h_M  = (const float*)d_in[1];
  const int* mask_V = (const int*)d_in[2];
  const int* mask_attend = (const int*)d_in[3];
  const float* Wh1 = (const float*)d_in[4];
  const float* Wv1 = (const float*)d_in[5];
  const float* Ws1 = (const float*)d_in[6];
  const float* bs1 = (const float*)d_in[7];
  const float* Wh2 = (const float*)d_in[8];
  const float* Wv2 = (const float*)d_in[9];
  const float* Ws2 = (const float*)d_in[10];
  const float* bs2 = (const float*)d_in[11];
  const float* Wh3 = (const float*)d_in[12];
  const float* Wv3 = (const float*)d_in[13];
  const float* Ws3 = (const float*)d_in[14];
  const float* bs3 = (const float*)d_in[15];
  const float* Wh4 = (const float*)d_in[16];
  const float* Wv4 = (const float*)d_in[17];
  const float* Ws4 = (const float*)d_in[18];
  const float* bs4 = (const float*)d_in[19];
  const float* Wh5 = (const float*)d_in[20];
  const float* Wv5 = (const float*)d_in[21];
  const float* Ws5 = (const float*)d_in[22];
  const float* bs5 = (const float*)d_in[23];
  const float* ln0_g = (const float*)d_in[24];
  const float* ln0_b = (const float*)d_in[25];
  const float* ln1_g = (const float*)d_in[26];
  const float* ln1_b = (const float*)d_in[27];
  float* out = (float*)d_out;

  float* wsf = (float*)d_ws;
  float* s1bg = wsf + WS_S1B;
  float* vhbg = wsf + WS_VHB;
  ushort* wsb = (ushort*)(wsf + WS_WSB);

  prep_weights<<<dim3(182), dim3(256), 0, stream>>>(Ws1, Ws2, Ws3, wsb);
  prep_node<<<dim3(NNODE), dim3(192), 0, stream>>>(h_V, Ws1, bs1, Wh1, s1bg, vhbg);
  mpnn_fused<<<dim3(NNODE), dim3(256), 0, stream>>>(
      h_V, h_M, mask_V, mask_attend,
      Wh1, Wv1, Wv2, bs2, Wv3, bs3, Wh2, Wh3,
      Wh4, Wv4, Ws4, bs4, Wh5, Wv5, Ws5, bs5,
      ln0_g, ln0_b, ln1_g, ln1_b, s1bg, vhbg, wsb, out);
}